// Round 1
// baseline (404.510 us; speedup 1.0000x reference)
//
#include <hip/hip_runtime.h>

// RewardTripletLoss: sim/gram GEMMs (bf16 MFMA) + per-row loss + FastAP rewards.
// ws layout: [0,32MB) sim/gram bf16 (reused sequentially); +32MB: Abf (1MB);
// +33MB: Rbf (1MB); +34MB: loss[4096] f32; +16KB: reward[4096] f32.

#define N_ROWS 4096
#define DIM 128
#define L_BINS 1601

typedef __bf16 bf16x8 __attribute__((ext_vector_type(8)));
typedef float f32x4 __attribute__((ext_vector_type(4)));

__device__ __forceinline__ unsigned short f32_to_bf16(float f) {
    unsigned int u = __float_as_uint(f);
    u = (u + 0x7FFFu + ((u >> 16) & 1u)) >> 16;
    return (unsigned short)u;
}

__device__ __forceinline__ float bf16_to_f32(unsigned short h) {
    return __uint_as_float(((unsigned int)h) << 16);
}

__global__ __launch_bounds__(256) void cvt_bf16_kernel(const float* __restrict__ in,
                                                       unsigned short* __restrict__ out,
                                                       int count) {
    for (int idx = blockIdx.x * 256 + threadIdx.x; idx < count; idx += gridDim.x * 256)
        out[idx] = f32_to_bf16(in[idx]);
}

// C[i][j] = sum_k A[i][k]*B[j][k]; A: M x K bf16 row-major, B: N x K bf16 row-major.
// One wave per 16x16 output tile; K=128 -> 4 MFMAs.
__global__ __launch_bounds__(256) void gemm_bt_kernel(const unsigned short* __restrict__ A,
                                                      const unsigned short* __restrict__ B,
                                                      unsigned short* __restrict__ C,
                                                      int M, int N, int K) {
    int gwave = blockIdx.x * 4 + (threadIdx.x >> 6);
    int lane = threadIdx.x & 63;
    int tiles_n = N >> 4;
    int tm = gwave / tiles_n;
    int tn = gwave - tm * tiles_n;
    if (tm >= (M >> 4)) return;

    int row_a = tm * 16 + (lane & 15);
    int row_b = tn * 16 + (lane & 15);
    int kbase = (lane >> 4) * 8;

    f32x4 acc = {0.f, 0.f, 0.f, 0.f};
    const unsigned short* pa = A + (size_t)row_a * K + kbase;
    const unsigned short* pb = B + (size_t)row_b * K + kbase;
    for (int kk = 0; kk < K; kk += 32) {
        bf16x8 a = *(const bf16x8*)(pa + kk);
        bf16x8 b = *(const bf16x8*)(pb + kk);
        acc = __builtin_amdgcn_mfma_f32_16x16x32_bf16(a, b, acc, 0, 0, 0);
    }
    int col = tn * 16 + (lane & 15);
    int row0 = tm * 16 + (lane >> 4) * 4;
    for (int r = 0; r < 4; ++r)
        C[(size_t)(row0 + r) * N + col] = f32_to_bf16(acc[r]);
}

// One block per row: pass1 row maxima (pos/neg), pass2 conditional sums.
__global__ __launch_bounds__(256) void loss_kernel(const unsigned short* __restrict__ sim,
                                                   const int* __restrict__ tcol,
                                                   const int* __restrict__ trow,
                                                   float* __restrict__ loss,
                                                   int n, int m) {
    __shared__ float r1[256], r2[256];
    const float NEG_INF = -__builtin_huge_valf();
    int i = blockIdx.x;
    int t = threadIdx.x;
    int myt = tcol[i];

    float pmax = NEG_INF, nmax = NEG_INF;
    for (int j = t; j < m; j += 256) {
        float s = bf16_to_f32(sim[(size_t)i * m + j]);
        bool same = (trow[j] == myt);
        if (same) {
            if (j != i && s > pmax) pmax = s;
        } else {
            if (s > nmax) nmax = s;
        }
    }
    r1[t] = pmax; r2[t] = nmax;
    __syncthreads();
    for (int off = 128; off > 0; off >>= 1) {
        if (t < off) { r1[t] = fmaxf(r1[t], r1[t + off]); r2[t] = fmaxf(r2[t], r2[t + off]); }
        __syncthreads();
    }
    float pm = r1[0], nm = r2[0];
    __syncthreads();

    float thr_n = nm + 0.1f;                 // pos selected when sim < neg_max + margin
    float thr_p = fmaxf(0.6f, pm) - 0.1f;    // neg selected when sim > thr
    float pl = 0.f, nl = 0.f;
    for (int j = t; j < m; j += 256) {
        float s = bf16_to_f32(sim[(size_t)i * m + j]);
        bool same = (trow[j] == myt);
        if (same) {
            if (j != i && s < thr_n) pl += 1.f - s;
        } else {
            if (s > thr_p) nl += s;
        }
    }
    r1[t] = pl; r2[t] = nl;
    __syncthreads();
    for (int off = 128; off > 0; off >>= 1) {
        if (t < off) { r1[t] += r1[t + off]; r2[t] += r2[t + off]; }
        __syncthreads();
    }
    if (t == 0) loss[i] = (pm > NEG_INF) ? (r1[0] + r2[0]) : 0.f;
}

// One block per row: soft-histogram (triangular) FastAP with LDS hist + block scan.
__global__ __launch_bounds__(256) void fastap_kernel(const unsigned short* __restrict__ gram,
                                                     const int* __restrict__ labels,
                                                     float* __restrict__ reward,
                                                     int n) {
    __shared__ float h_pos[L_BINS];
    __shared__ float h_all[L_BINS];
    __shared__ float sp[256], sa[256];
    int i = blockIdx.x;
    int t = threadIdx.x;

    for (int b = t; b < L_BINS; b += 256) { h_pos[b] = 0.f; h_all[b] = 0.f; }
    __syncthreads();

    int li = labels[i];
    int npos = 0;
    const float delta = 4.0f / 1600.0f;
    for (int j = t; j < n; j += 256) {
        if (j == i) continue;
        float g = bf16_to_f32(gram[(size_t)i * n + j]);
        float d2 = fminf(fmaxf(2.f - 2.f * g, 0.f), 4.f);
        float tt = d2 / delta;
        float fl = floorf(tt);
        int i0 = (int)fl;
        if (i0 < 0) i0 = 0;
        if (i0 > L_BINS - 1) i0 = L_BINS - 1;
        int i1 = i0 + 1;
        if (i1 > L_BINS - 1) i1 = L_BINS - 1;
        float frac = tt - fl;
        bool pos = (labels[j] == li);
        atomicAdd(&h_all[i0], 1.f - frac);
        atomicAdd(&h_all[i1], frac);
        if (pos) {
            atomicAdd(&h_pos[i0], 1.f - frac);
            atomicAdd(&h_pos[i1], frac);
            npos++;
        }
    }
    __syncthreads();

    // Chunked inclusive scan: each thread owns 7 consecutive bins (256*7=1792>=1601).
    const int CH = 7;
    int base = t * CH;
    float lp[CH], la[CH];
    float cp = 0.f, ca = 0.f;
    for (int k = 0; k < CH; ++k) {
        int idx = base + k;
        float hp = (idx < L_BINS) ? h_pos[idx] : 0.f;
        float ha = (idx < L_BINS) ? h_all[idx] : 0.f;
        cp += hp; ca += ha;
        lp[k] = cp; la[k] = ca;
    }
    sp[t] = cp; sa[t] = ca;
    __syncthreads();
    for (int off = 1; off < 256; off <<= 1) {  // Hillis-Steele inclusive scan
        float vp = 0.f, va = 0.f;
        if (t >= off) { vp = sp[t - off]; va = sa[t - off]; }
        __syncthreads();
        sp[t] += vp; sa[t] += va;
        __syncthreads();
    }
    float offp = sp[t] - cp, offa = sa[t] - ca;  // exclusive offsets
    __syncthreads();

    float ap = 0.f;
    for (int k = 0; k < CH; ++k) {
        int idx = base + k;
        if (idx < L_BINS) {
            float hp = h_pos[idx];
            float Hp = lp[k] + offp;
            float Ha = la[k] + offa;
            if (Ha > 0.f) ap += hp * Hp / Ha;
        }
    }
    sp[t] = ap; sa[t] = (float)npos;
    __syncthreads();
    for (int off = 128; off > 0; off >>= 1) {
        if (t < off) { sp[t] += sp[t + off]; sa[t] += sa[t + off]; }
        __syncthreads();
    }
    if (t == 0) {
        float np_ = sa[0];
        reward[i] = (np_ > 0.f) ? sp[0] / fmaxf(np_, 1.f) : 0.f;
    }
}

__global__ __launch_bounds__(256) void final_kernel(const float* __restrict__ loss,
                                                    const float* __restrict__ reward,
                                                    float* __restrict__ out, int n) {
    __shared__ float r[256];
    int t = threadIdx.x;
    float s = 0.f;
    for (int j = t; j < n; j += 256) s += loss[j] * (1.f - reward[j]);
    r[t] = s;
    __syncthreads();
    for (int off = 128; off > 0; off >>= 1) {
        if (t < off) r[t] += r[t + off];
        __syncthreads();
    }
    if (t == 0) out[0] = r[0] / (float)n;
}

extern "C" void kernel_launch(void* const* d_in, const int* in_sizes, int n_in,
                              void* d_out, int out_size, void* d_ws, size_t ws_size,
                              hipStream_t stream) {
    const float* inputs_col = (const float*)d_in[0];
    const int* targets_col = (const int*)d_in[1];
    const float* inputs_row = (const float*)d_in[2];
    const int* targets_row = (const int*)d_in[3];
    const int* reward_labels = (const int*)d_in[4];
    float* out = (float*)d_out;

    const int n = N_ROWS, m = N_ROWS, d = DIM;
    char* ws = (char*)d_ws;
    unsigned short* simbuf = (unsigned short*)ws;                       // 32 MB, reused for gram
    unsigned short* Abf = (unsigned short*)(ws + (size_t)33554432);     // 1 MB
    unsigned short* Rbf = (unsigned short*)(ws + (size_t)33554432 + 1048576);
    float* loss = (float*)(ws + (size_t)33554432 + 2 * 1048576);
    float* reward = loss + n;

    // 1) f32 -> bf16 conversions
    cvt_bf16_kernel<<<2048, 256, 0, stream>>>(inputs_col, Abf, n * d);
    cvt_bf16_kernel<<<2048, 256, 0, stream>>>(inputs_row, Rbf, m * d);

    // 2) sim = col @ row^T (bf16 out)
    int gemm_blocks = (n / 16) * (m / 16) / 4;  // 4 waves/block
    gemm_bt_kernel<<<gemm_blocks, 256, 0, stream>>>(Abf, Rbf, simbuf, n, m, d);

    // 3) per-row triplet loss
    loss_kernel<<<n, 256, 0, stream>>>(simbuf, targets_col, targets_row, loss, n, m);

    // 4) gram = col @ col^T (overwrites simbuf; stream order guarantees loss read finished)
    gemm_bt_kernel<<<gemm_blocks, 256, 0, stream>>>(Abf, Abf, simbuf, n, n, d);

    // 5) per-row FastAP reward
    fastap_kernel<<<n, 256, 0, stream>>>(simbuf, reward_labels, reward, n);

    // 6) final scalar
    final_kernel<<<1, 256, 0, stream>>>(loss, reward, out, n);
}

// Round 2
// 244.111 us; speedup vs baseline: 1.6571x; 1.6571x over previous
//
#include <hip/hip_runtime.h>

// RewardTripletLoss: sim/gram GEMMs (bf16 MFMA) + per-row loss + FastAP rewards.
// R1: FastAP histograms switched from float LDS atomics (HIP emits a CAS loop ->
// lane-serialized ~120cyc round trips, the 180us hotspot) to fixed-point u32
// ds_add_u32 (native, fire-and-forget). Vectorized uint4 (8x bf16) row reads;
// loss_kernel stages sim row + mask in LDS on pass 1.

#define N_ROWS 4096
#define DIM 128
#define L_BINS 1601
#define WSCALE 65536.0f

typedef __bf16 bf16x8 __attribute__((ext_vector_type(8)));
typedef float f32x4 __attribute__((ext_vector_type(4)));

__device__ __forceinline__ unsigned short f32_to_bf16(float f) {
    unsigned int u = __float_as_uint(f);
    u = (u + 0x7FFFu + ((u >> 16) & 1u)) >> 16;
    return (unsigned short)u;
}

__device__ __forceinline__ float bf16_lo(unsigned int u) {  // low 16 bits as bf16
    return __uint_as_float(u << 16);
}
__device__ __forceinline__ float bf16_hi(unsigned int u) {  // high 16 bits as bf16
    return __uint_as_float(u & 0xFFFF0000u);
}

__global__ __launch_bounds__(256) void cvt_bf16_kernel(const float* __restrict__ in,
                                                       unsigned short* __restrict__ out,
                                                       int count) {
    for (int idx = blockIdx.x * 256 + threadIdx.x; idx < count; idx += gridDim.x * 256)
        out[idx] = f32_to_bf16(in[idx]);
}

// C[i][j] = sum_k A[i][k]*B[j][k]; A: M x K bf16 row-major, B: N x K bf16 row-major.
// One wave per 16x16 output tile; K=128 -> 4 MFMAs.
__global__ __launch_bounds__(256) void gemm_bt_kernel(const unsigned short* __restrict__ A,
                                                      const unsigned short* __restrict__ B,
                                                      unsigned short* __restrict__ C,
                                                      int M, int N, int K) {
    int gwave = blockIdx.x * 4 + (threadIdx.x >> 6);
    int lane = threadIdx.x & 63;
    int tiles_n = N >> 4;
    int tm = gwave / tiles_n;
    int tn = gwave - tm * tiles_n;
    if (tm >= (M >> 4)) return;

    int row_a = tm * 16 + (lane & 15);
    int row_b = tn * 16 + (lane & 15);
    int kbase = (lane >> 4) * 8;

    f32x4 acc = {0.f, 0.f, 0.f, 0.f};
    const unsigned short* pa = A + (size_t)row_a * K + kbase;
    const unsigned short* pb = B + (size_t)row_b * K + kbase;
    for (int kk = 0; kk < K; kk += 32) {
        bf16x8 a = *(const bf16x8*)(pa + kk);
        bf16x8 b = *(const bf16x8*)(pb + kk);
        acc = __builtin_amdgcn_mfma_f32_16x16x32_bf16(a, b, acc, 0, 0, 0);
    }
    int col = tn * 16 + (lane & 15);
    int row0 = tm * 16 + (lane >> 4) * 4;
    for (int r = 0; r < 4; ++r)
        C[(size_t)(row0 + r) * N + col] = f32_to_bf16(acc[r]);
}

// One block per row: pass1 stages sim row (f32) + same-mask in LDS while finding
// row maxima; pass2 conditional sums from LDS only.
__global__ __launch_bounds__(256) void loss_kernel(const unsigned short* __restrict__ sim,
                                                   const int* __restrict__ tcol,
                                                   const int* __restrict__ trow,
                                                   float* __restrict__ loss,
                                                   int n, int m) {
    __shared__ float ssim[N_ROWS];
    __shared__ char smask[N_ROWS];
    __shared__ float r1[256], r2[256];
    const float NEG_INF = -__builtin_huge_valf();
    int i = blockIdx.x;
    int t = threadIdx.x;
    int myt = tcol[i];

    const uint4* simv = (const uint4*)(sim + (size_t)i * m);
    const int4* labv = (const int4*)trow;

    float pmax = NEG_INF, nmax = NEG_INF;
    for (int v = t; v < (m >> 3); v += 256) {
        uint4 pk = simv[v];
        int4 l0 = labv[v * 2];
        int4 l1 = labv[v * 2 + 1];
        int j0 = v << 3;
        float s[8];
        s[0] = bf16_lo(pk.x); s[1] = bf16_hi(pk.x);
        s[2] = bf16_lo(pk.y); s[3] = bf16_hi(pk.y);
        s[4] = bf16_lo(pk.z); s[5] = bf16_hi(pk.z);
        s[6] = bf16_lo(pk.w); s[7] = bf16_hi(pk.w);
        int lab[8] = {l0.x, l0.y, l0.z, l0.w, l1.x, l1.y, l1.z, l1.w};
#pragma unroll
        for (int k = 0; k < 8; ++k) {
            int j = j0 + k;
            bool same = (lab[k] == myt);
            ssim[j] = s[k];
            smask[j] = same ? 1 : 0;
            if (same) {
                if (j != i && s[k] > pmax) pmax = s[k];
            } else {
                if (s[k] > nmax) nmax = s[k];
            }
        }
    }
    r1[t] = pmax; r2[t] = nmax;
    __syncthreads();
    for (int off = 128; off > 0; off >>= 1) {
        if (t < off) { r1[t] = fmaxf(r1[t], r1[t + off]); r2[t] = fmaxf(r2[t], r2[t + off]); }
        __syncthreads();
    }
    float pm = r1[0], nm = r2[0];
    __syncthreads();

    float thr_n = nm + 0.1f;                 // pos selected when sim < neg_max + margin
    float thr_p = fmaxf(0.6f, pm) - 0.1f;    // neg selected when sim > thr
    float pl = 0.f, nl = 0.f;
    for (int j = t; j < m; j += 256) {
        float s = ssim[j];
        if (smask[j]) {
            if (j != i && s < thr_n) pl += 1.f - s;
        } else {
            if (s > thr_p) nl += s;
        }
    }
    r1[t] = pl; r2[t] = nl;
    __syncthreads();
    for (int off = 128; off > 0; off >>= 1) {
        if (t < off) { r1[t] += r1[t + off]; r2[t] += r2[t + off]; }
        __syncthreads();
    }
    if (t == 0) loss[i] = (pm > NEG_INF) ? (r1[0] + r2[0]) : 0.f;
}

// One block per row: fixed-point (x65536) u32 soft histogram via native ds_add_u32,
// exact integer block scan, float AP accumulation.
__global__ __launch_bounds__(256) void fastap_kernel(const unsigned short* __restrict__ gram,
                                                     const int* __restrict__ labels,
                                                     float* __restrict__ reward,
                                                     int n) {
    __shared__ unsigned int h_pos[L_BINS];
    __shared__ unsigned int h_all[L_BINS];
    __shared__ unsigned int sp[256], sa[256];
    __shared__ float fr[256];
    __shared__ int ir[256];
    int i = blockIdx.x;
    int t = threadIdx.x;

    for (int b = t; b < L_BINS; b += 256) { h_pos[b] = 0u; h_all[b] = 0u; }
    __syncthreads();

    int li = labels[i];
    int npos = 0;
    const uint4* gv = (const uint4*)(gram + (size_t)i * n);
    const int4* labv = (const int4*)labels;

    for (int v = t; v < (n >> 3); v += 256) {
        uint4 pk = gv[v];
        int4 l0 = labv[v * 2];
        int4 l1 = labv[v * 2 + 1];
        int j0 = v << 3;
        float s[8];
        s[0] = bf16_lo(pk.x); s[1] = bf16_hi(pk.x);
        s[2] = bf16_lo(pk.y); s[3] = bf16_hi(pk.y);
        s[4] = bf16_lo(pk.z); s[5] = bf16_hi(pk.z);
        s[6] = bf16_lo(pk.w); s[7] = bf16_hi(pk.w);
        int lab[8] = {l0.x, l0.y, l0.z, l0.w, l1.x, l1.y, l1.z, l1.w};
#pragma unroll
        for (int k = 0; k < 8; ++k) {
            int j = j0 + k;
            if (j == i) continue;
            float d2 = fminf(fmaxf(2.f - 2.f * s[k], 0.f), 4.f);
            float tt = d2 * 400.0f;  // / (4/1600)
            float fl = floorf(tt);
            int i0 = (int)fl;
            if (i0 > L_BINS - 1) i0 = L_BINS - 1;
            int i1 = i0 + 1;
            if (i1 > L_BINS - 1) i1 = L_BINS - 1;
            unsigned int w1 = (unsigned int)((tt - fl) * WSCALE);
            unsigned int w0 = 65536u - w1;
            atomicAdd(&h_all[i0], w0);
            atomicAdd(&h_all[i1], w1);
            if (lab[k] == li) {
                atomicAdd(&h_pos[i0], w0);
                atomicAdd(&h_pos[i1], w1);
                npos++;
            }
        }
    }
    __syncthreads();

    // Chunked inclusive scan: each thread owns 7 consecutive bins (256*7=1792>=1601).
    const int CH = 7;
    int base = t * CH;
    unsigned int lp[CH], la[CH];
    unsigned int cp = 0u, ca = 0u;
    for (int k = 0; k < CH; ++k) {
        int idx = base + k;
        unsigned int hp = (idx < L_BINS) ? h_pos[idx] : 0u;
        unsigned int ha = (idx < L_BINS) ? h_all[idx] : 0u;
        cp += hp; ca += ha;
        lp[k] = cp; la[k] = ca;
    }
    sp[t] = cp; sa[t] = ca;
    __syncthreads();
    for (int off = 1; off < 256; off <<= 1) {  // Hillis-Steele inclusive scan
        unsigned int vp = 0u, va = 0u;
        if (t >= off) { vp = sp[t - off]; va = sa[t - off]; }
        __syncthreads();
        sp[t] += vp; sa[t] += va;
        __syncthreads();
    }
    unsigned int offp = sp[t] - cp, offa = sa[t] - ca;  // exclusive offsets
    __syncthreads();

    float ap = 0.f;
    for (int k = 0; k < CH; ++k) {
        int idx = base + k;
        if (idx < L_BINS) {
            unsigned int hp = h_pos[idx];
            unsigned int Ha = la[k] + offa;
            if (hp > 0u && Ha > 0u) {
                float Hp = (float)(lp[k] + offp);
                ap += (float)hp * Hp / (float)Ha;
            }
        }
    }
    fr[t] = ap; ir[t] = npos;
    __syncthreads();
    for (int off = 128; off > 0; off >>= 1) {
        if (t < off) { fr[t] += fr[t + off]; ir[t] += ir[t + off]; }
        __syncthreads();
    }
    if (t == 0) {
        float np_ = (float)ir[0];
        reward[i] = (np_ > 0.f) ? fr[0] * (1.0f / WSCALE) / fmaxf(np_, 1.f) : 0.f;
    }
}

__global__ __launch_bounds__(256) void final_kernel(const float* __restrict__ loss,
                                                    const float* __restrict__ reward,
                                                    float* __restrict__ out, int n) {
    __shared__ float r[256];
    int t = threadIdx.x;
    float s = 0.f;
    for (int j = t; j < n; j += 256) s += loss[j] * (1.f - reward[j]);
    r[t] = s;
    __syncthreads();
    for (int off = 128; off > 0; off >>= 1) {
        if (t < off) r[t] += r[t + off];
        __syncthreads();
    }
    if (t == 0) out[0] = r[0] / (float)n;
}

extern "C" void kernel_launch(void* const* d_in, const int* in_sizes, int n_in,
                              void* d_out, int out_size, void* d_ws, size_t ws_size,
                              hipStream_t stream) {
    const float* inputs_col = (const float*)d_in[0];
    const int* targets_col = (const int*)d_in[1];
    const float* inputs_row = (const float*)d_in[2];
    const int* targets_row = (const int*)d_in[3];
    const int* reward_labels = (const int*)d_in[4];
    float* out = (float*)d_out;

    const int n = N_ROWS, m = N_ROWS, d = DIM;
    char* ws = (char*)d_ws;
    unsigned short* simbuf = (unsigned short*)ws;                       // 32 MB, reused for gram
    unsigned short* Abf = (unsigned short*)(ws + (size_t)33554432);     // 1 MB
    unsigned short* Rbf = (unsigned short*)(ws + (size_t)33554432 + 1048576);
    float* loss = (float*)(ws + (size_t)33554432 + 2 * 1048576);
    float* reward = loss + n;

    // 1) f32 -> bf16 conversions
    cvt_bf16_kernel<<<2048, 256, 0, stream>>>(inputs_col, Abf, n * d);
    cvt_bf16_kernel<<<2048, 256, 0, stream>>>(inputs_row, Rbf, m * d);

    // 2) sim = col @ row^T (bf16 out)
    int gemm_blocks = (n / 16) * (m / 16) / 4;  // 4 waves/block
    gemm_bt_kernel<<<gemm_blocks, 256, 0, stream>>>(Abf, Rbf, simbuf, n, m, d);

    // 3) per-row triplet loss
    loss_kernel<<<n, 256, 0, stream>>>(simbuf, targets_col, targets_row, loss, n, m);

    // 4) gram = col @ col^T (overwrites simbuf; stream order guarantees loss read finished)
    gemm_bt_kernel<<<gemm_blocks, 256, 0, stream>>>(Abf, Abf, simbuf, n, n, d);

    // 5) per-row FastAP reward
    fastap_kernel<<<n, 256, 0, stream>>>(simbuf, reward_labels, reward, n);

    // 6) final scalar
    final_kernel<<<1, 256, 0, stream>>>(loss, reward, out, n);
}

// Round 3
// 150.730 us; speedup vs baseline: 2.6837x; 1.6195x over previous
//
#include <hip/hip_runtime.h>

// RewardTripletLoss: sim/gram GEMMs (bf16 MFMA) + per-row loss + FastAP rewards.
// R2: GEMM rewritten m97-style — 128x128 tile/block, K=128 single shot,
// global_load_lds(16B) staging into 64KB LDS, 4 waves x 64x64 quadrant
// (4x4 of 16x16x32 MFMA). Replaces the latency-bound 1-wave-per-16x16 kernel
// (67us, MfmaUtil 2.3%).

#define N_ROWS 4096
#define DIM 128
#define TILE 128
#define L_BINS 1601
#define WSCALE 65536.0f

typedef __bf16 bf16x8 __attribute__((ext_vector_type(8)));
typedef float f32x4 __attribute__((ext_vector_type(4)));

__device__ __forceinline__ unsigned short f32_to_bf16(float f) {
    unsigned int u = __float_as_uint(f);
    u = (u + 0x7FFFu + ((u >> 16) & 1u)) >> 16;
    return (unsigned short)u;
}

__device__ __forceinline__ float bf16_lo(unsigned int u) {  // low 16 bits as bf16
    return __uint_as_float(u << 16);
}
__device__ __forceinline__ float bf16_hi(unsigned int u) {  // high 16 bits as bf16
    return __uint_as_float(u & 0xFFFF0000u);
}

// Async global->LDS, 16B per lane. LDS dest is wave-uniform base + lane*16.
__device__ __forceinline__ void async_copy16(const void* g, void* l) {
    __builtin_amdgcn_global_load_lds(
        (const __attribute__((address_space(1))) unsigned int*)g,
        (__attribute__((address_space(3))) unsigned int*)l, 16, 0, 0);
}

__global__ __launch_bounds__(256) void cvt_bf16_kernel(const float* __restrict__ in,
                                                       unsigned short* __restrict__ out,
                                                       int count) {
    for (int idx = blockIdx.x * 256 + threadIdx.x; idx < count; idx += gridDim.x * 256)
        out[idx] = f32_to_bf16(in[idx]);
}

// C[i][j] = sum_k A[i][k]*B[j][k]; A,B row-major [4096][128] bf16, C [4096][4096] bf16.
// Grid (32,32); block 256 = 4 waves; 128x128 tile; K=128 in one LDS-resident shot.
__global__ __launch_bounds__(256) void gemm_tile_kernel(const unsigned short* __restrict__ A,
                                                        const unsigned short* __restrict__ B,
                                                        unsigned short* __restrict__ C,
                                                        int N) {
    __shared__ unsigned short As[TILE * DIM];  // 32 KB (tile is contiguous in global)
    __shared__ unsigned short Bs[TILE * DIM];  // 32 KB
    int w = threadIdx.x >> 6;
    int lane = threadIdx.x & 63;
    int tm = blockIdx.y, tn = blockIdx.x;

    const char* ga = (const char*)(A + (size_t)tm * TILE * DIM);
    const char* gb = (const char*)(B + (size_t)tn * TILE * DIM);
#pragma unroll
    for (int it = 0; it < 8; ++it) {
        int off = (w * 8 + it) * 1024;  // bytes; wave-chunk of 1KB (64 lanes x 16B)
        async_copy16(ga + off + lane * 16, (char*)As + off);
        async_copy16(gb + off + lane * 16, (char*)Bs + off);
    }
    __syncthreads();  // drains vmcnt -> LDS tiles complete

    int wm = (w & 1) * 64;
    int wn = (w >> 1) * 64;
    int quad = lane >> 4;
    int l15 = lane & 15;

    f32x4 acc[4][4] = {};
#pragma unroll
    for (int kk = 0; kk < 4; ++kk) {
        int kb = kk * 32 + quad * 8;
        bf16x8 af[4], bfr[4];
#pragma unroll
        for (int mi = 0; mi < 4; ++mi)
            af[mi] = *(const bf16x8*)&As[(wm + mi * 16 + l15) * DIM + kb];
#pragma unroll
        for (int ni = 0; ni < 4; ++ni)
            bfr[ni] = *(const bf16x8*)&Bs[(wn + ni * 16 + l15) * DIM + kb];
#pragma unroll
        for (int mi = 0; mi < 4; ++mi)
#pragma unroll
            for (int ni = 0; ni < 4; ++ni)
                acc[mi][ni] = __builtin_amdgcn_mfma_f32_16x16x32_bf16(af[mi], bfr[ni], acc[mi][ni], 0, 0, 0);
    }

#pragma unroll
    for (int mi = 0; mi < 4; ++mi) {
        int row0 = tm * TILE + wm + mi * 16 + quad * 4;
#pragma unroll
        for (int ni = 0; ni < 4; ++ni) {
            int col = tn * TILE + wn + ni * 16 + l15;
#pragma unroll
            for (int r = 0; r < 4; ++r)
                C[(size_t)(row0 + r) * N + col] = f32_to_bf16(acc[mi][ni][r]);
        }
    }
}

// One block per row: pass1 stages sim row (f32) + same-mask in LDS while finding
// row maxima; pass2 conditional sums from LDS only.
__global__ __launch_bounds__(256) void loss_kernel(const unsigned short* __restrict__ sim,
                                                   const int* __restrict__ tcol,
                                                   const int* __restrict__ trow,
                                                   float* __restrict__ loss,
                                                   int n, int m) {
    __shared__ float ssim[N_ROWS];
    __shared__ char smask[N_ROWS];
    __shared__ float r1[256], r2[256];
    const float NEG_INF = -__builtin_huge_valf();
    int i = blockIdx.x;
    int t = threadIdx.x;
    int myt = tcol[i];

    const uint4* simv = (const uint4*)(sim + (size_t)i * m);
    const int4* labv = (const int4*)trow;

    float pmax = NEG_INF, nmax = NEG_INF;
    for (int v = t; v < (m >> 3); v += 256) {
        uint4 pk = simv[v];
        int4 l0 = labv[v * 2];
        int4 l1 = labv[v * 2 + 1];
        int j0 = v << 3;
        float s[8];
        s[0] = bf16_lo(pk.x); s[1] = bf16_hi(pk.x);
        s[2] = bf16_lo(pk.y); s[3] = bf16_hi(pk.y);
        s[4] = bf16_lo(pk.z); s[5] = bf16_hi(pk.z);
        s[6] = bf16_lo(pk.w); s[7] = bf16_hi(pk.w);
        int lab[8] = {l0.x, l0.y, l0.z, l0.w, l1.x, l1.y, l1.z, l1.w};
#pragma unroll
        for (int k = 0; k < 8; ++k) {
            int j = j0 + k;
            bool same = (lab[k] == myt);
            ssim[j] = s[k];
            smask[j] = same ? 1 : 0;
            if (same) {
                if (j != i && s[k] > pmax) pmax = s[k];
            } else {
                if (s[k] > nmax) nmax = s[k];
            }
        }
    }
    r1[t] = pmax; r2[t] = nmax;
    __syncthreads();
    for (int off = 128; off > 0; off >>= 1) {
        if (t < off) { r1[t] = fmaxf(r1[t], r1[t + off]); r2[t] = fmaxf(r2[t], r2[t + off]); }
        __syncthreads();
    }
    float pm = r1[0], nm = r2[0];
    __syncthreads();

    float thr_n = nm + 0.1f;                 // pos selected when sim < neg_max + margin
    float thr_p = fmaxf(0.6f, pm) - 0.1f;    // neg selected when sim > thr
    float pl = 0.f, nl = 0.f;
    for (int j = t; j < m; j += 256) {
        float s = ssim[j];
        if (smask[j]) {
            if (j != i && s < thr_n) pl += 1.f - s;
        } else {
            if (s > thr_p) nl += s;
        }
    }
    r1[t] = pl; r2[t] = nl;
    __syncthreads();
    for (int off = 128; off > 0; off >>= 1) {
        if (t < off) { r1[t] += r1[t + off]; r2[t] += r2[t + off]; }
        __syncthreads();
    }
    if (t == 0) loss[i] = (pm > NEG_INF) ? (r1[0] + r2[0]) : 0.f;
}

// One block per row: fixed-point (x65536) u32 soft histogram via native ds_add_u32,
// exact integer block scan, float AP accumulation.
__global__ __launch_bounds__(256) void fastap_kernel(const unsigned short* __restrict__ gram,
                                                     const int* __restrict__ labels,
                                                     float* __restrict__ reward,
                                                     int n) {
    __shared__ unsigned int h_pos[L_BINS];
    __shared__ unsigned int h_all[L_BINS];
    __shared__ unsigned int sp[256], sa[256];
    __shared__ float fr[256];
    __shared__ int ir[256];
    int i = blockIdx.x;
    int t = threadIdx.x;

    for (int b = t; b < L_BINS; b += 256) { h_pos[b] = 0u; h_all[b] = 0u; }
    __syncthreads();

    int li = labels[i];
    int npos = 0;
    const uint4* gv = (const uint4*)(gram + (size_t)i * n);
    const int4* labv = (const int4*)labels;

    for (int v = t; v < (n >> 3); v += 256) {
        uint4 pk = gv[v];
        int4 l0 = labv[v * 2];
        int4 l1 = labv[v * 2 + 1];
        int j0 = v << 3;
        float s[8];
        s[0] = bf16_lo(pk.x); s[1] = bf16_hi(pk.x);
        s[2] = bf16_lo(pk.y); s[3] = bf16_hi(pk.y);
        s[4] = bf16_lo(pk.z); s[5] = bf16_hi(pk.z);
        s[6] = bf16_lo(pk.w); s[7] = bf16_hi(pk.w);
        int lab[8] = {l0.x, l0.y, l0.z, l0.w, l1.x, l1.y, l1.z, l1.w};
#pragma unroll
        for (int k = 0; k < 8; ++k) {
            int j = j0 + k;
            if (j == i) continue;
            float d2 = fminf(fmaxf(2.f - 2.f * s[k], 0.f), 4.f);
            float tt = d2 * 400.0f;  // / (4/1600)
            float fl = floorf(tt);
            int i0 = (int)fl;
            if (i0 > L_BINS - 1) i0 = L_BINS - 1;
            int i1 = i0 + 1;
            if (i1 > L_BINS - 1) i1 = L_BINS - 1;
            unsigned int w1 = (unsigned int)((tt - fl) * WSCALE);
            unsigned int w0 = 65536u - w1;
            atomicAdd(&h_all[i0], w0);
            atomicAdd(&h_all[i1], w1);
            if (lab[k] == li) {
                atomicAdd(&h_pos[i0], w0);
                atomicAdd(&h_pos[i1], w1);
                npos++;
            }
        }
    }
    __syncthreads();

    // Chunked inclusive scan: each thread owns 7 consecutive bins (256*7=1792>=1601).
    const int CH = 7;
    int base = t * CH;
    unsigned int lp[CH], la[CH];
    unsigned int cp = 0u, ca = 0u;
    for (int k = 0; k < CH; ++k) {
        int idx = base + k;
        unsigned int hp = (idx < L_BINS) ? h_pos[idx] : 0u;
        unsigned int ha = (idx < L_BINS) ? h_all[idx] : 0u;
        cp += hp; ca += ha;
        lp[k] = cp; la[k] = ca;
    }
    sp[t] = cp; sa[t] = ca;
    __syncthreads();
    for (int off = 1; off < 256; off <<= 1) {  // Hillis-Steele inclusive scan
        unsigned int vp = 0u, va = 0u;
        if (t >= off) { vp = sp[t - off]; va = sa[t - off]; }
        __syncthreads();
        sp[t] += vp; sa[t] += va;
        __syncthreads();
    }
    unsigned int offp = sp[t] - cp, offa = sa[t] - ca;  // exclusive offsets
    __syncthreads();

    float ap = 0.f;
    for (int k = 0; k < CH; ++k) {
        int idx = base + k;
        if (idx < L_BINS) {
            unsigned int hp = h_pos[idx];
            unsigned int Ha = la[k] + offa;
            if (hp > 0u && Ha > 0u) {
                float Hp = (float)(lp[k] + offp);
                ap += (float)hp * Hp / (float)Ha;
            }
        }
    }
    fr[t] = ap; ir[t] = npos;
    __syncthreads();
    for (int off = 128; off > 0; off >>= 1) {
        if (t < off) { fr[t] += fr[t + off]; ir[t] += ir[t + off]; }
        __syncthreads();
    }
    if (t == 0) {
        float np_ = (float)ir[0];
        reward[i] = (np_ > 0.f) ? fr[0] * (1.0f / WSCALE) / fmaxf(np_, 1.f) : 0.f;
    }
}

__global__ __launch_bounds__(256) void final_kernel(const float* __restrict__ loss,
                                                    const float* __restrict__ reward,
                                                    float* __restrict__ out, int n) {
    __shared__ float r[256];
    int t = threadIdx.x;
    float s = 0.f;
    for (int j = t; j < n; j += 256) s += loss[j] * (1.f - reward[j]);
    r[t] = s;
    __syncthreads();
    for (int off = 128; off > 0; off >>= 1) {
        if (t < off) r[t] += r[t + off];
        __syncthreads();
    }
    if (t == 0) out[0] = r[0] / (float)n;
}

extern "C" void kernel_launch(void* const* d_in, const int* in_sizes, int n_in,
                              void* d_out, int out_size, void* d_ws, size_t ws_size,
                              hipStream_t stream) {
    const float* inputs_col = (const float*)d_in[0];
    const int* targets_col = (const int*)d_in[1];
    const float* inputs_row = (const float*)d_in[2];
    const int* targets_row = (const int*)d_in[3];
    const int* reward_labels = (const int*)d_in[4];
    float* out = (float*)d_out;

    const int n = N_ROWS, m = N_ROWS, d = DIM;
    char* ws = (char*)d_ws;
    unsigned short* simbuf = (unsigned short*)ws;                       // 32 MB, reused for gram
    unsigned short* Abf = (unsigned short*)(ws + (size_t)33554432);     // 1 MB
    unsigned short* Rbf = (unsigned short*)(ws + (size_t)33554432 + 1048576);
    float* loss = (float*)(ws + (size_t)33554432 + 2 * 1048576);
    float* reward = loss + n;

    // 1) f32 -> bf16 conversions
    cvt_bf16_kernel<<<2048, 256, 0, stream>>>(inputs_col, Abf, n * d);
    cvt_bf16_kernel<<<2048, 256, 0, stream>>>(inputs_row, Rbf, m * d);

    // 2) sim = col @ row^T (bf16 out)
    dim3 ggrid(n / TILE, n / TILE);
    gemm_tile_kernel<<<ggrid, 256, 0, stream>>>(Abf, Rbf, simbuf, m);

    // 3) per-row triplet loss
    loss_kernel<<<n, 256, 0, stream>>>(simbuf, targets_col, targets_row, loss, n, m);

    // 4) gram = col @ col^T (overwrites simbuf; stream order guarantees loss read finished)
    gemm_tile_kernel<<<ggrid, 256, 0, stream>>>(Abf, Abf, simbuf, n);

    // 5) per-row FastAP reward
    fastap_kernel<<<n, 256, 0, stream>>>(simbuf, reward_labels, reward, n);

    // 6) final scalar
    final_kernel<<<1, 256, 0, stream>>>(loss, reward, out, n);
}

// Round 4
// 135.764 us; speedup vs baseline: 2.9795x; 1.1102x over previous
//
#include <hip/hip_runtime.h>

// RewardTripletLoss: sim/gram GEMMs (bf16 MFMA) + per-row loss + FastAP rewards.
// R3: loss -> wave-per-row, register-resident (no LDS/barriers, shfl reductions);
// fastap -> u64 packed histogram (pos<<32 | all) = 2 native ds_add_u64 per elem
// (was 4 u32) + shuffle-scan (2 barriers, was 16); cvt fused to 1 launch; both
// GEMMs fused to one launch (blockIdx.z) writing sim + gram to separate buffers.

#define N_ROWS 4096
#define DIM 128
#define TILE 128
#define L_BINS 1601

typedef __bf16 bf16x8 __attribute__((ext_vector_type(8)));
typedef float f32x4 __attribute__((ext_vector_type(4)));

__device__ __forceinline__ unsigned short f32_to_bf16(float f) {
    unsigned int u = __float_as_uint(f);
    u = (u + 0x7FFFu + ((u >> 16) & 1u)) >> 16;
    return (unsigned short)u;
}

__device__ __forceinline__ float bf16_lo(unsigned int u) {
    return __uint_as_float(u << 16);
}
__device__ __forceinline__ float bf16_hi(unsigned int u) {
    return __uint_as_float(u & 0xFFFF0000u);
}

__device__ __forceinline__ void unpack8(uint4 pk, float* s) {
    s[0] = bf16_lo(pk.x); s[1] = bf16_hi(pk.x);
    s[2] = bf16_lo(pk.y); s[3] = bf16_hi(pk.y);
    s[4] = bf16_lo(pk.z); s[5] = bf16_hi(pk.z);
    s[6] = bf16_lo(pk.w); s[7] = bf16_hi(pk.w);
}

// Async global->LDS, 16B per lane. LDS dest is wave-uniform base + lane*16.
__device__ __forceinline__ void async_copy16(const void* g, void* l) {
    __builtin_amdgcn_global_load_lds(
        (const __attribute__((address_space(1))) unsigned int*)g,
        (__attribute__((address_space(3))) unsigned int*)l, 16, 0, 0);
}

// Both f32->bf16 conversions in one launch.
__global__ __launch_bounds__(256) void cvt2_kernel(const float4* __restrict__ a,
                                                   const float4* __restrict__ b,
                                                   ushort4* __restrict__ oa,
                                                   ushort4* __restrict__ ob,
                                                   int nvec) {
    for (int idx = blockIdx.x * 256 + threadIdx.x; idx < 2 * nvec; idx += gridDim.x * 256) {
        bool second = idx >= nvec;
        int k = second ? idx - nvec : idx;
        float4 v = second ? b[k] : a[k];
        ushort4 o;
        o.x = f32_to_bf16(v.x); o.y = f32_to_bf16(v.y);
        o.z = f32_to_bf16(v.z); o.w = f32_to_bf16(v.w);
        if (second) ob[k] = o; else oa[k] = o;
    }
}

// C[i][j] = sum_k A[i][k]*Bz[j][k]. Grid (32,32,2): z=0 -> B0->C0 (sim), z=1 -> B1->C1 (gram).
__global__ __launch_bounds__(256) void gemm_tile_kernel(const unsigned short* __restrict__ A,
                                                        const unsigned short* __restrict__ B0,
                                                        const unsigned short* __restrict__ B1,
                                                        unsigned short* __restrict__ C0,
                                                        unsigned short* __restrict__ C1,
                                                        int N) {
    __shared__ unsigned short As[TILE * DIM];  // 32 KB (tile contiguous in global)
    __shared__ unsigned short Bs[TILE * DIM];  // 32 KB
    int w = threadIdx.x >> 6;
    int lane = threadIdx.x & 63;
    int tm = blockIdx.y, tn = blockIdx.x;
    const unsigned short* B = blockIdx.z ? B1 : B0;
    unsigned short* C = blockIdx.z ? C1 : C0;

    const char* ga = (const char*)(A + (size_t)tm * TILE * DIM);
    const char* gb = (const char*)(B + (size_t)tn * TILE * DIM);
#pragma unroll
    for (int it = 0; it < 8; ++it) {
        int off = (w * 8 + it) * 1024;  // wave-chunk of 1KB (64 lanes x 16B)
        async_copy16(ga + off + lane * 16, (char*)As + off);
        async_copy16(gb + off + lane * 16, (char*)Bs + off);
    }
    __syncthreads();

    int wm = (w & 1) * 64;
    int wn = (w >> 1) * 64;
    int quad = lane >> 4;
    int l15 = lane & 15;

    f32x4 acc[4][4] = {};
#pragma unroll
    for (int kk = 0; kk < 4; ++kk) {
        int kb = kk * 32 + quad * 8;
        bf16x8 af[4], bfr[4];
#pragma unroll
        for (int mi = 0; mi < 4; ++mi)
            af[mi] = *(const bf16x8*)&As[(wm + mi * 16 + l15) * DIM + kb];
#pragma unroll
        for (int ni = 0; ni < 4; ++ni)
            bfr[ni] = *(const bf16x8*)&Bs[(wn + ni * 16 + l15) * DIM + kb];
#pragma unroll
        for (int mi = 0; mi < 4; ++mi)
#pragma unroll
            for (int ni = 0; ni < 4; ++ni)
                acc[mi][ni] = __builtin_amdgcn_mfma_f32_16x16x32_bf16(af[mi], bfr[ni], acc[mi][ni], 0, 0, 0);
    }

#pragma unroll
    for (int mi = 0; mi < 4; ++mi) {
        int row0 = tm * TILE + wm + mi * 16 + quad * 4;
#pragma unroll
        for (int ni = 0; ni < 4; ++ni) {
            int col = tn * TILE + wn + ni * 16 + l15;
#pragma unroll
            for (int r = 0; r < 4; ++r)
                C[(size_t)(row0 + r) * N + col] = f32_to_bf16(acc[mi][ni][r]);
        }
    }
}

// One WAVE per row. 64 lanes x 64 elems, packed bf16 in registers, pos/neg as
// 64-bit lane bitmasks, shfl_xor reductions. No LDS, no barriers.
__global__ __launch_bounds__(256) void loss_kernel(const unsigned short* __restrict__ sim,
                                                   const int* __restrict__ tcol,
                                                   const int* __restrict__ trow,
                                                   float* __restrict__ loss,
                                                   int n, int m) {
    int i = (blockIdx.x * 256 + threadIdx.x) >> 6;  // row = global wave id
    int lane = threadIdx.x & 63;
    int myt = tcol[i];

    const uint4* simv = (const uint4*)(sim + (size_t)i * m);
    const int4* labv = (const int4*)trow;

    uint4 pk[8];
    unsigned long long posm = 0ull, negm = 0ull;
    float pmax = -3e38f, nmax = -3e38f;
#pragma unroll
    for (int v = 0; v < 8; ++v) {
        int vi = v * 64 + lane;
        pk[v] = simv[vi];
        int4 l0 = labv[2 * vi];
        int4 l1 = labv[2 * vi + 1];
        int j0 = vi * 8;
        float s[8];
        unpack8(pk[v], s);
        int lab[8] = {l0.x, l0.y, l0.z, l0.w, l1.x, l1.y, l1.z, l1.w};
#pragma unroll
        for (int k = 0; k < 8; ++k) {
            int j = j0 + k;
            bool same = (lab[k] == myt);
            bool posf = same && (j != i);
            if (posf) pmax = fmaxf(pmax, s[k]);
            if (!same) nmax = fmaxf(nmax, s[k]);
            posm |= ((unsigned long long)posf) << (v * 8 + k);
            negm |= ((unsigned long long)(!same)) << (v * 8 + k);
        }
    }
#pragma unroll
    for (int off = 32; off > 0; off >>= 1) {
        pmax = fmaxf(pmax, __shfl_xor(pmax, off));
        nmax = fmaxf(nmax, __shfl_xor(nmax, off));
    }

    float thr_n = nmax + 0.1f;               // pos selected when sim < neg_max + margin
    float thr_p = fmaxf(0.6f, pmax) - 0.1f;  // neg selected when sim > thr
    float pl = 0.f, nl = 0.f;
#pragma unroll
    for (int v = 0; v < 8; ++v) {
        float s[8];
        unpack8(pk[v], s);
#pragma unroll
        for (int k = 0; k < 8; ++k) {
            int bit = v * 8 + k;
            bool posf = (posm >> bit) & 1ull;
            bool negf = (negm >> bit) & 1ull;
            pl += (posf && s[k] < thr_n) ? 1.f - s[k] : 0.f;
            nl += (negf && s[k] > thr_p) ? s[k] : 0.f;
        }
    }
    float tot = pl + nl;
#pragma unroll
    for (int off = 32; off > 0; off >>= 1) tot += __shfl_xor(tot, off);
    if (lane == 0) loss[i] = (pmax > -1e30f) ? tot : 0.f;
}

// One block per row. u64 histogram: low 32 = total weight (x65536 fixed point),
// high 32 = positive weight. One native ds_add_u64 per bin pair -> 2 atomics/elem.
// Shuffle-based block scan (2 barriers).
__global__ __launch_bounds__(256) void fastap_kernel(const unsigned short* __restrict__ gram,
                                                     const int* __restrict__ labels,
                                                     float* __restrict__ reward,
                                                     int n) {
    __shared__ unsigned long long hist[L_BINS];  // 12.8 KB
    __shared__ unsigned long long wsum[4];
    __shared__ float apw[4];
    __shared__ int npw[4];
    int i = blockIdx.x;
    int t = threadIdx.x;
    int w = t >> 6;
    int lane = t & 63;

    for (int b = t; b < L_BINS; b += 256) hist[b] = 0ull;
    __syncthreads();

    int li = labels[i];
    int npos = 0;
    const uint4* gv = (const uint4*)(gram + (size_t)i * n);
    const int4* labv = (const int4*)labels;

    for (int v = t; v < (n >> 3); v += 256) {
        uint4 pk = gv[v];
        int4 l0 = labv[2 * v];
        int4 l1 = labv[2 * v + 1];
        int j0 = v << 3;
        float s[8];
        unpack8(pk, s);
        int lab[8] = {l0.x, l0.y, l0.z, l0.w, l1.x, l1.y, l1.z, l1.w};
#pragma unroll
        for (int k = 0; k < 8; ++k) {
            int j = j0 + k;
            float d2 = fminf(fmaxf(2.f - 2.f * s[k], 0.f), 4.f);
            float tt = d2 * 400.0f;  // / (4/1600)
            float fl = floorf(tt);
            int i0 = (int)fl;
            if (i0 > L_BINS - 1) i0 = L_BINS - 1;
            int i1 = i0 + 1;
            if (i1 > L_BINS - 1) i1 = L_BINS - 1;
            unsigned int w1 = (unsigned int)((tt - fl) * 65536.0f);
            unsigned int w0 = 65536u - w1;
            bool diag = (j == i);
            if (diag) { w0 = 0u; w1 = 0u; }
            bool posf = (lab[k] == li) && !diag;
            unsigned long long hi = posf ? 1ull : 0ull;
            atomicAdd(&hist[i0], (unsigned long long)w0 | ((hi * w0) << 32));
            atomicAdd(&hist[i1], (unsigned long long)w1 | ((hi * w1) << 32));
            npos += posf ? 1 : 0;
        }
    }
    __syncthreads();

    // Chunked scan: 7 bins/thread; shuffle inclusive scan of thread totals.
    const int CH = 7;
    int base = t * CH;
    unsigned long long lc[CH];
    unsigned long long run = 0ull;
#pragma unroll
    for (int k = 0; k < CH; ++k) {
        int idx = base + k;
        unsigned long long h = (idx < L_BINS) ? hist[idx] : 0ull;
        run += h;
        lc[k] = run;
    }
    unsigned long long tsum = run;
    unsigned long long sc = tsum;
#pragma unroll
    for (int off = 1; off < 64; off <<= 1) {
        unsigned long long v2 = __shfl_up(sc, off);
        if (lane >= off) sc += v2;
    }
    if (lane == 63) wsum[w] = sc;
    __syncthreads();
    unsigned long long woff = 0ull;
    for (int ww = 0; ww < w; ++ww) woff += wsum[ww];
    unsigned long long throff = woff + sc - tsum;  // exclusive offset for this thread

    float ap = 0.f;
#pragma unroll
    for (int k = 0; k < CH; ++k) {
        int idx = base + k;
        if (idx < L_BINS) {
            unsigned long long h = hist[idx];
            unsigned int hp = (unsigned int)(h >> 32);
            if (hp) {
                unsigned long long cum = lc[k] + throff;
                unsigned int Hp = (unsigned int)(cum >> 32);
                unsigned int Ha = (unsigned int)cum;
                ap += (float)hp * (float)Hp / (float)Ha;
            }
        }
    }
#pragma unroll
    for (int off = 32; off > 0; off >>= 1) {
        ap += __shfl_xor(ap, off);
        npos += __shfl_xor(npos, off);
    }
    if (lane == 0) { apw[w] = ap; npw[w] = npos; }
    __syncthreads();
    if (t == 0) {
        float A = apw[0] + apw[1] + apw[2] + apw[3];
        int np = npw[0] + npw[1] + npw[2] + npw[3];
        reward[i] = (np > 0) ? A * (1.0f / 65536.0f) / (float)np : 0.f;
    }
}

__global__ __launch_bounds__(256) void final_kernel(const float* __restrict__ loss,
                                                    const float* __restrict__ reward,
                                                    float* __restrict__ out, int n) {
    __shared__ float r[256];
    int t = threadIdx.x;
    float s = 0.f;
    for (int j = t; j < n; j += 256) s += loss[j] * (1.f - reward[j]);
    r[t] = s;
    __syncthreads();
    for (int off = 128; off > 0; off >>= 1) {
        if (t < off) r[t] += r[t + off];
        __syncthreads();
    }
    if (t == 0) out[0] = r[0] / (float)n;
}

extern "C" void kernel_launch(void* const* d_in, const int* in_sizes, int n_in,
                              void* d_out, int out_size, void* d_ws, size_t ws_size,
                              hipStream_t stream) {
    const float* inputs_col = (const float*)d_in[0];
    const int* targets_col = (const int*)d_in[1];
    const float* inputs_row = (const float*)d_in[2];
    const int* targets_row = (const int*)d_in[3];
    const int* reward_labels = (const int*)d_in[4];
    float* out = (float*)d_out;

    const int n = N_ROWS, m = N_ROWS, d = DIM;
    char* ws = (char*)d_ws;
    const size_t MB = 1048576;
    unsigned short* simbuf = (unsigned short*)ws;                 // 32 MB
    unsigned short* grambuf = (unsigned short*)(ws + 32 * MB);    // 32 MB
    unsigned short* Abf = (unsigned short*)(ws + 64 * MB);        // 1 MB
    unsigned short* Rbf = (unsigned short*)(ws + 65 * MB);        // 1 MB
    float* loss = (float*)(ws + 66 * MB);
    float* reward = loss + n;

    // 1) f32 -> bf16 (both arrays, one launch)
    cvt2_kernel<<<512, 256, 0, stream>>>((const float4*)inputs_col, (const float4*)inputs_row,
                                         (ushort4*)Abf, (ushort4*)Rbf, n * d / 4);

    // 2) sim = col@row^T and gram = col@col^T in one launch
    dim3 ggrid(n / TILE, n / TILE, 2);
    gemm_tile_kernel<<<ggrid, 256, 0, stream>>>(Abf, Rbf, Abf, simbuf, grambuf, m);

    // 3) per-row triplet loss (wave per row)
    loss_kernel<<<n / 4, 256, 0, stream>>>(simbuf, targets_col, targets_row, loss, n, m);

    // 4) per-row FastAP reward
    fastap_kernel<<<n, 256, 0, stream>>>(grambuf, reward_labels, reward, n);

    // 5) final scalar
    final_kernel<<<1, 256, 0, stream>>>(loss, reward, out, n);
}